// Round 7
// baseline (237.277 us; speedup 1.0000x reference)
//
#include <hip/hip_runtime.h>
#include <cstdint>
#include <cstddef>

#define B_ 2
#define N_ 2048
#define C_ 256
#define H_ 64
#define W_ 176
#define TW 16
#define NTX 11                    // 176/16 tiles per row
#define NTILES (B_*H_*NTX)        // 1408
#define CAP 2048                  // exact upper bound per tile
#define G_ 16                     // gaussians per splat chunk
#define AS 20                     // mlp activation LDS stride (floats, 80B)

// ---------------------------------------------------------------------------
// global->LDS direct DMA: each lane moves 16B.
// ---------------------------------------------------------------------------
__device__ __forceinline__ void gl_lds16(const float* gsrc, float* ldst)
{
    auto gp = (const __attribute__((address_space(1))) unsigned int*)(uintptr_t)gsrc;
    auto lp = (__attribute__((address_space(3))) unsigned int*)(unsigned int)(uintptr_t)ldst;
    __builtin_amdgcn_global_load_lds(gp, lp, 16, 0, 0);
}

// ---------------------------------------------------------------------------
// Fused param + bin: block = 8 gaussians x 32 y-row candidates.
// pp[i][8]: 0:px 1:py 2:1/sx 3:1/sy 4:w 5:(sx+sy)/2
// ---------------------------------------------------------------------------
__global__ __launch_bounds__(256)
void parambin_kernel(const float* __restrict__ g, const float* __restrict__ intr,
                     float* __restrict__ pp, int* __restrict__ counts,
                     int* __restrict__ lists)
{
    const int tid = threadIdx.x;
    const int i = blockIdx.x * 8 + (tid >> 5);
    const int j = tid & 31;
    const float* gi = g + (size_t)i * 14;
    const float x = gi[0], y = gi[1], z = gi[2];
    const float s5 = gi[5], s6 = gi[6], wv = gi[12];
    const float k00 = intr[0], k01 = intr[1], k02 = intr[2];
    const float k10 = intr[3], k11 = intr[4], k12 = intr[5];
    const float k20 = intr[6], k21 = intr[7], k22 = intr[8];
    const float projx = k00 * x + k01 * y + k02 * z;
    const float projy = k10 * x + k11 * y + k12 * z;
    const float projz = k20 * x + k21 * y + k22 * z;
    const float inv = 1.f / (projz + 1e-6f);
    const float scale_x = (float)W_ / k02 * 0.5f;
    const float scale_y = (float)H_ / k12 * 0.5f;
    const float px = projx * inv * scale_x;
    const float py = projy * inv * scale_y;
    const bool valid = z > 0.1f;
    const bool inb = (px >= 0.f) && (px < (float)W_) && (py >= 0.f) && (py < (float)H_);
    const bool mask = valid && inb;
    const float sx = fmaxf(s5 * scale_x, 1.f);
    const float sy = fmaxf(s6 * scale_y, 1.f);
    if (j == 0) {
        float4* o = (float4*)(pp + (size_t)i * 8);
        o[0] = make_float4(px, py, 1.f / sx, 1.f / sy);
        o[1] = make_float4(wv, 0.5f * (sx + sy), 0.f, 0.f);
    }
    if (!mask) return;
    const float rx = 3.f * sx, ry = 3.f * sy;
    const int ymin = max(0, (int)floorf(py - ry));
    const int ymax = min(H_ - 1, (int)ceilf(py + ry));
    const int yy = ymin + j;
    if (yy > ymax) return;
    const int tmin = max(0, (int)floorf((px - rx - (float)(TW - 1)) * (1.f / TW)));
    const int tmax = min(NTX - 1, (int)ceilf((px + rx) * (1.f / TW)));
    const int b = i / N_, n = i - b * N_;
    for (int t = tmin; t <= tmax; ++t) {
        const int tile = (b * H_ + yy) * NTX + t;
        const int slot = atomicAdd(&counts[tile], 1);
        lists[(size_t)tile * CAP + slot] = n;
    }
}

// ---------------------------------------------------------------------------
// Fused MLP: 16 rows/block, 512 threads, grid 256. Thread = 1 col x RPT rows;
// row-group wave-uniform -> activation read = uniform LDS b128 broadcast.
// RPT = NCOL/32 (L1:2, L2:4, L3-5:8) -> deep ILP per weight load.
// ---------------------------------------------------------------------------
template<int K, int NCOL, bool RELU>
__device__ __forceinline__ void mlp_layer(const float* __restrict__ w,
                                          const float* __restrict__ bias,
                                          const float* actIn, float* actOut,
                                          int tid)
{
    constexpr int RG = 512 / NCOL;        // row groups
    constexpr int RPT = 16 / RG;          // rows per thread
    const int col = tid % NCOL;
    const int r0 = (tid / NCOL) * RPT;    // wave-uniform
    float acc[RPT];
    const float bv = bias[col];
#pragma unroll
    for (int r = 0; r < RPT; ++r) acc[r] = bv;
#pragma unroll 8
    for (int k = 0; k < K; ++k) {
        const float wv = w[(size_t)k * NCOL + col];
        float av[RPT];
        if (RPT == 8) {
            const float4 a0 = *(const float4*)&actIn[k * AS + r0];
            const float4 a1 = *(const float4*)&actIn[k * AS + r0 + 4];
            av[0] = a0.x; av[1] = a0.y; av[2] = a0.z; av[3] = a0.w;
            av[4] = a1.x; av[5] = a1.y; av[6] = a1.z; av[7] = a1.w;
        } else if (RPT == 4) {
            const float4 a0 = *(const float4*)&actIn[k * AS + r0];
            av[0] = a0.x; av[1] = a0.y; av[2] = a0.z; av[3] = a0.w;
        } else {
            const float2 a0 = *(const float2*)&actIn[k * AS + r0];
            av[0] = a0.x; av[1] = a0.y;
        }
#pragma unroll
        for (int r = 0; r < RPT; ++r)
            acc[r] = fmaf(av[r], wv, acc[r]);
    }
#pragma unroll
    for (int r = 0; r < RPT; ++r) {
        float v = acc[r];
        if (RELU) v = fmaxf(v, 0.f);
        actOut[col * AS + r0 + r] = v;
    }
}

__global__ __launch_bounds__(512)
void mlp_kernel(const float* __restrict__ g,
                const float* __restrict__ w1, const float* __restrict__ b1,
                const float* __restrict__ w2, const float* __restrict__ b2,
                const float* __restrict__ w3, const float* __restrict__ b3,
                const float* __restrict__ fw1, const float* __restrict__ fb1,
                const float* __restrict__ fw2, const float* __restrict__ fb2,
                float* __restrict__ ft)
{
    __shared__ __align__(16) float bufA[256 * AS];
    __shared__ __align__(16) float bufB[256 * AS];
    const int tid = threadIdx.x;
    const int row0 = blockIdx.x * 16;

    if (tid < 224) {                      // stage g transposed: [k][r], 14x16
        const int k = tid / 16, r = tid % 16;
        bufA[k * AS + r] = g[(size_t)(row0 + r) * 14 + k];
    }
    __syncthreads();
    mlp_layer<14, 64, true >(w1,  b1,  bufA, bufB, tid); __syncthreads();
    mlp_layer<64, 128, true >(w2,  b2,  bufB, bufA, tid); __syncthreads();
    mlp_layer<128, 256, false>(w3,  b3,  bufA, bufB, tid); __syncthreads();
    mlp_layer<256, 256, true >(fw1, fb1, bufB, bufA, tid); __syncthreads();
    {   // layer 5 straight to global
        const int col = tid % 256;
        const int r0 = (tid / 256) * 8;   // wave-uniform
        float acc[8];
        const float bv = fb2[col];
#pragma unroll
        for (int r = 0; r < 8; ++r) acc[r] = bv;
#pragma unroll 8
        for (int k = 0; k < 256; ++k) {
            const float wv = fw2[(size_t)k * 256 + col];
            const float4 a0 = *(const float4*)&bufA[k * AS + r0];
            const float4 a1 = *(const float4*)&bufA[k * AS + r0 + 4];
            acc[0] = fmaf(a0.x, wv, acc[0]);
            acc[1] = fmaf(a0.y, wv, acc[1]);
            acc[2] = fmaf(a0.z, wv, acc[2]);
            acc[3] = fmaf(a0.w, wv, acc[3]);
            acc[4] = fmaf(a1.x, wv, acc[4]);
            acc[5] = fmaf(a1.y, wv, acc[5]);
            acc[6] = fmaf(a1.z, wv, acc[6]);
            acc[7] = fmaf(a1.w, wv, acc[7]);
        }
#pragma unroll
        for (int r = 0; r < 8; ++r)
            ft[(size_t)(row0 + r0 + r) * 256 + col] = acc[r];
    }
}

// ---------------------------------------------------------------------------
// Splat: persistent blocks (grid 512, 2/CU) popping tiles off a global
// cursor (dynamic load balance). Per tile: 1-barrier chunk pipeline with
// global_load_lds double-buffered feats staging, 4ch x 4px phase-B tile.
// ---------------------------------------------------------------------------
__global__ __launch_bounds__(256)
void splat_kernel(const float* __restrict__ pp, const int* __restrict__ lists,
                  const int* __restrict__ counts, const float* __restrict__ feats,
                  int* __restrict__ cursor, float* __restrict__ out)
{
    __shared__ __align__(16) float feats_s[2][G_ * C_];   // 2 x 16 KB
    __shared__ __align__(16) float gws[2][G_ * 20];       // padded rows
    __shared__ int tile_s;

    const int tid = threadIdx.x;
    const int gg  = tid >> 4;             // phase A: gaussian slot
    const int pxi = tid & 15;             // phase A: pixel
    const int cg  = tid >> 2;             // phase B: channel group (4 ch)
    const int pg  = tid & 3;              // phase B: pixel group (4 px)
    const int lane = tid & 63;
    const int wid  = tid >> 6;

    for (;;) {
        __syncthreads();                  // protect tile_s + LDS from prev tile
        if (tid == 0) tile_s = atomicAdd(cursor, 1);
        __syncthreads();
        const int bid = tile_s;
        if (bid >= NTILES) break;

        const int txi = bid % NTX;
        const int y   = (bid / NTX) % H_;
        const int b   = bid / (NTX * H_);
        const int x0  = txi * TW;
        const float fy = (float)y;
        const float fx = (float)(x0 + pxi);
        const int cnt = counts[bid];
        const int* mylist = lists + (size_t)bid * CAP;
        const int bN = b * N_;

        float acc[16];
#pragma unroll
        for (int t = 0; t < 16; ++t) acc[t] = 0.f;
        float densp = 0.f, uncp = 0.f;

        if (cnt > 0) {
            // prologue: DMA chunk 0 into buffer 0
#pragma unroll
            for (int rr = 0; rr < 4; ++rr) {
                const int r = 4 * wid + rr;
                const int n = mylist[min(r, cnt - 1)];
                gl_lds16(feats + (size_t)(bN + n) * C_ + lane * 4,
                         &feats_s[0][r * C_ + lane * 4]);
            }
            const int nchunks = (cnt + G_ - 1) / G_;
            for (int c = 0; c < nchunks; ++c) {
                const int buf = c & 1;
                const int m = min(G_, cnt - c * G_);
                if (gg < m) {
                    const int n = mylist[c * G_ + gg];
                    const float4 e0 = ((const float4*)pp)[(size_t)(bN + n) * 2 + 0];
                    const float4 e1 = ((const float4*)pp)[(size_t)(bN + n) * 2 + 1];
                    const float dyn = (fy - e0.y) * e0.w;
                    const float dxn = (fx - e0.x) * e0.z;
                    const float dist = dyn * dyn + dxn * dxn;
                    float gv = 0.f;
                    if (dist < 9.f) gv = __expf(-0.5f * dist) * e1.x;
                    gws[buf][gg * 20 + pxi] = gv;
                    densp += gv;
                    uncp  += gv * e1.y;
                }
                __syncthreads();          // drains this wave's DMA too
                if (c + 1 < nchunks) {    // DMA c+1, overlaps phase B below
#pragma unroll
                    for (int rr = 0; rr < 4; ++rr) {
                        const int r = 4 * wid + rr;
                        const int n = mylist[min((c + 1) * G_ + r, cnt - 1)];
                        gl_lds16(feats + (size_t)(bN + n) * C_ + lane * 4,
                                 &feats_s[buf ^ 1][r * C_ + lane * 4]);
                    }
                }
                for (int q = 0; q < m; ++q) {
                    const float4 fv  = *(const float4*)&feats_s[buf][q * C_ + 4 * cg];
                    const float4 gw4 = *(const float4*)&gws[buf][q * 20 + 4 * pg];
                    acc[0]  = fmaf(fv.x, gw4.x, acc[0]);
                    acc[1]  = fmaf(fv.x, gw4.y, acc[1]);
                    acc[2]  = fmaf(fv.x, gw4.z, acc[2]);
                    acc[3]  = fmaf(fv.x, gw4.w, acc[3]);
                    acc[4]  = fmaf(fv.y, gw4.x, acc[4]);
                    acc[5]  = fmaf(fv.y, gw4.y, acc[5]);
                    acc[6]  = fmaf(fv.y, gw4.z, acc[6]);
                    acc[7]  = fmaf(fv.y, gw4.w, acc[7]);
                    acc[8]  = fmaf(fv.z, gw4.x, acc[8]);
                    acc[9]  = fmaf(fv.z, gw4.y, acc[9]);
                    acc[10] = fmaf(fv.z, gw4.z, acc[10]);
                    acc[11] = fmaf(fv.z, gw4.w, acc[11]);
                    acc[12] = fmaf(fv.w, gw4.x, acc[12]);
                    acc[13] = fmaf(fv.w, gw4.y, acc[13]);
                    acc[14] = fmaf(fv.w, gw4.z, acc[14]);
                    acc[15] = fmaf(fv.w, gw4.w, acc[15]);
                }
            }
        }

        // reduce densp/uncp over the 16 gg-groups per pixel
        __syncthreads();
        float* red_d = &feats_s[0][0];    // 16 x 20
        float* red_u = &feats_s[0][512];
        red_d[gg * 20 + pxi] = densp;
        red_u[gg * 20 + pxi] = uncp;
        __syncthreads();
        for (int s = 8; s > 0; s >>= 1) {
            if (gg < s) {
                red_d[gg * 20 + pxi] += red_d[(gg + s) * 20 + pxi];
                red_u[gg * 20 + pxi] += red_u[(gg + s) * 20 + pxi];
            }
            __syncthreads();
        }

        float dclip[4];
#pragma unroll
        for (int jj = 0; jj < 4; ++jj) dclip[jj] = fmaxf(red_d[4 * pg + jj], 1e-6f);

#pragma unroll
        for (int cc = 0; cc < 4; ++cc) {
            const int ch = 4 * cg + cc;
            float4 v;
            v.x = acc[cc * 4 + 0] / dclip[0];
            v.y = acc[cc * 4 + 1] / dclip[1];
            v.z = acc[cc * 4 + 2] / dclip[2];
            v.w = acc[cc * 4 + 3] / dclip[3];
            *(float4*)(out + (((size_t)b * C_ + ch) * H_ + y) * W_ + x0 + 4 * pg) = v;
        }
        if (tid < TW) {
            const size_t pix = ((size_t)b * H_ + y) * W_ + x0 + tid;
            float* unc_o = out + (size_t)B_ * C_ * H_ * W_;
            float* den_o = unc_o + (size_t)B_ * H_ * W_;
            const float d = fmaxf(red_d[tid], 1e-6f);
            unc_o[pix] = red_u[tid] / d;
            den_o[pix] = d;
        }
    }
}

// ---------------------------------------------------------------------------
extern "C" void kernel_launch(void* const* d_in, const int* in_sizes, int n_in,
                              void* d_out, int out_size, void* d_ws, size_t ws_size,
                              hipStream_t stream)
{
    const float* g    = (const float*)d_in[0];
    const float* intr = (const float*)d_in[1];
    const float* w1   = (const float*)d_in[2];
    const float* b1   = (const float*)d_in[3];
    const float* w2   = (const float*)d_in[4];
    const float* b2   = (const float*)d_in[5];
    const float* w3   = (const float*)d_in[6];
    const float* b3   = (const float*)d_in[7];
    const float* fw1  = (const float*)d_in[8];
    const float* fb1  = (const float*)d_in[9];
    const float* fw2  = (const float*)d_in[10];
    const float* fb2  = (const float*)d_in[11];

    float* ws = (float*)d_ws;
    const int rows = B_ * N_;                          // 4096
    float* ft     = ws;                                // 4096*256 floats (4 MB)
    float* pp     = ft + (size_t)rows * C_;            // 4096*8 floats (128 KB)
    int*   counts = (int*)(pp + (size_t)8 * rows);     // 1408 ints
    int*   cursor = counts + NTILES;                   // 1 int
    int*   lists  = cursor + 1;                        // 1408*2048 ints (11.5 MB)

    hipMemsetAsync(counts, 0, (NTILES + 1) * sizeof(int), stream);
    parambin_kernel<<<dim3(rows / 8), dim3(256), 0, stream>>>(g, intr, pp, counts, lists);
    mlp_kernel<<<dim3(rows / 16), dim3(512), 0, stream>>>(g, w1, b1, w2, b2, w3, b3,
                                                          fw1, fb1, fw2, fb2, ft);
    splat_kernel<<<dim3(512), dim3(256), 0, stream>>>(pp, lists, counts, ft,
                                                      cursor, (float*)d_out);
}

// Round 8
// 194.127 us; speedup vs baseline: 1.2223x; 1.2223x over previous
//
#include <hip/hip_runtime.h>
#include <cstdint>
#include <cstddef>

#define B_ 2
#define N_ 2048
#define C_ 256
#define H_ 64
#define W_ 176
#define TW 16
#define NTX 11                    // 176/16 tiles per row
#define NTILES (B_*H_*NTX)        // 1408
#define CAP 1024                  // per-tile list cap (avg ~120, est. peak ~400)
#define G_ 16                     // gaussians per splat chunk
#define SA 260                    // mlp act LDS stride (floats): 2-way-conflict-free, 16B-aligned

typedef short bf16x8 __attribute__((ext_vector_type(8)));
typedef float f32x4  __attribute__((ext_vector_type(4)));

__device__ __forceinline__ short f2bf(float f)   // RNE fp32->bf16
{
    unsigned u = __float_as_uint(f);
    return (short)((u + 0x7FFFu + ((u >> 16) & 1u)) >> 16);
}

// global->LDS direct DMA: each lane moves 16B.
__device__ __forceinline__ void gl_lds16(const float* gsrc, float* ldst)
{
    auto gp = (const __attribute__((address_space(1))) unsigned int*)(uintptr_t)gsrc;
    auto lp = (__attribute__((address_space(3))) unsigned int*)(unsigned int)(uintptr_t)ldst;
    __builtin_amdgcn_global_load_lds(gp, lp, 16, 0, 0);
}

// ---------------------------------------------------------------------------
// Fused param + bin + weight-convert.
// First: grid-stride fp32->bf16 transposed convert of w3/fw1/fw2 (all threads).
// Then: block = 8 gaussians x 32 y-rows binning (threads may early-return).
// pp[i][8]: 0:px 1:py 2:1/sx 3:1/sy 4:w 5:(sx+sy)/2
// ---------------------------------------------------------------------------
__global__ __launch_bounds__(256)
void parambin_kernel(const float* __restrict__ g, const float* __restrict__ intr,
                     const float* __restrict__ w3f, const float* __restrict__ fw1f,
                     const float* __restrict__ fw2f,
                     short* __restrict__ wt3, short* __restrict__ wt4,
                     short* __restrict__ wt5,
                     float* __restrict__ pp, int* __restrict__ counts,
                     int* __restrict__ lists)
{
    const int tid = threadIdx.x;
    const int gid = blockIdx.x * 256 + tid;
    // ---- weight convert (no early returns above this) ----
    for (int e = gid; e < 163840; e += 131072) {
        if (e < 32768) {
            const int k = e >> 8, n = e & 255;
            wt3[n * 128 + k] = f2bf(w3f[e]);
        } else if (e < 98304) {
            const int i = e - 32768, k = i >> 8, n = i & 255;
            wt4[n * 256 + k] = f2bf(fw1f[i]);
        } else {
            const int i = e - 98304, k = i >> 8, n = i & 255;
            wt5[n * 256 + k] = f2bf(fw2f[i]);
        }
    }
    // ---- bin ----
    const int i = blockIdx.x * 8 + (tid >> 5);
    const int j = tid & 31;
    const float* gi = g + (size_t)i * 14;
    const float x = gi[0], y = gi[1], z = gi[2];
    const float s5 = gi[5], s6 = gi[6], wv = gi[12];
    const float k00 = intr[0], k01 = intr[1], k02 = intr[2];
    const float k10 = intr[3], k11 = intr[4], k12 = intr[5];
    const float k20 = intr[6], k21 = intr[7], k22 = intr[8];
    const float projx = k00 * x + k01 * y + k02 * z;
    const float projy = k10 * x + k11 * y + k12 * z;
    const float projz = k20 * x + k21 * y + k22 * z;
    const float inv = 1.f / (projz + 1e-6f);
    const float scale_x = (float)W_ / k02 * 0.5f;
    const float scale_y = (float)H_ / k12 * 0.5f;
    const float px = projx * inv * scale_x;
    const float py = projy * inv * scale_y;
    const bool valid = z > 0.1f;
    const bool inb = (px >= 0.f) && (px < (float)W_) && (py >= 0.f) && (py < (float)H_);
    const bool mask = valid && inb;
    const float sx = fmaxf(s5 * scale_x, 1.f);
    const float sy = fmaxf(s6 * scale_y, 1.f);
    if (j == 0) {
        float4* o = (float4*)(pp + (size_t)i * 8);
        o[0] = make_float4(px, py, 1.f / sx, 1.f / sy);
        o[1] = make_float4(wv, 0.5f * (sx + sy), 0.f, 0.f);
    }
    if (!mask) return;
    const float rx = 3.f * sx, ry = 3.f * sy;
    const int ymin = max(0, (int)floorf(py - ry));
    const int ymax = min(H_ - 1, (int)ceilf(py + ry));
    const int yy = ymin + j;
    if (yy > ymax) return;
    const int tmin = max(0, (int)floorf((px - rx - (float)(TW - 1)) * (1.f / TW)));
    const int tmax = min(NTX - 1, (int)ceilf((px + rx) * (1.f / TW)));
    const int b = i / N_, n = i - b * N_;
    for (int t = tmin; t <= tmax; ++t) {
        const int tile = (b * H_ + yy) * NTX + t;
        const int slot = atomicAdd(&counts[tile], 1);
        if (slot < CAP) lists[(size_t)tile * CAP + slot] = n;
    }
}

// ---------------------------------------------------------------------------
// MFMA accumulate: D[16 x 64-per-wave] over K, A from LDS acts [m][k] (fp32,
// packed to bf16), B from global bf16 transposed [n][k] (16B frag loads).
// A-frag: a[j] = act[m=lane&15][ks*32 + (lane>>4)*8 + j]
// B-frag: b[j] = wt[(n0+lane&15)*K + ks*32 + (lane>>4)*8 + j]
// C/D:    D[row=(lane>>4)*4+reg][col=lane&15]
// ---------------------------------------------------------------------------
template<int K>
__device__ __forceinline__ void mfma_acc(const short* __restrict__ wt,
                                         const float* actIn, f32x4 (&acc)[4],
                                         int wv_, int quad, int ln15)
{
#pragma unroll
    for (int ks = 0; ks < K / 32; ++ks) {
        const int kb = ks * 32 + quad * 8;
        const float4 a0 = *(const float4*)&actIn[ln15 * SA + kb];
        const float4 a1 = *(const float4*)&actIn[ln15 * SA + kb + 4];
        bf16x8 af = { f2bf(a0.x), f2bf(a0.y), f2bf(a0.z), f2bf(a0.w),
                      f2bf(a1.x), f2bf(a1.y), f2bf(a1.z), f2bf(a1.w) };
#pragma unroll
        for (int tt = 0; tt < 4; ++tt) {
            const int n0 = (wv_ * 4 + tt) * 16;
            const bf16x8 bf = *(const bf16x8*)&wt[(size_t)(n0 + ln15) * K + kb];
            acc[tt] = __builtin_amdgcn_mfma_f32_16x16x32_bf16(af, bf, acc[tt], 0, 0, 0);
        }
    }
}

// ---------------------------------------------------------------------------
// Fused MLP: block = 16 rows, 256 threads (4 waves), grid 256.
// L1(14->64), L2(64->128) fp32 VALU; L3(128->256), L4, L5 (256->256) bf16 MFMA.
// Acts ping-pong in LDS as [m][k], stride SA.
// ---------------------------------------------------------------------------
__global__ __launch_bounds__(256)
void mlp_kernel(const float* __restrict__ g,
                const float* __restrict__ w1, const float* __restrict__ b1,
                const float* __restrict__ w2, const float* __restrict__ b2,
                const short* __restrict__ wt3, const float* __restrict__ b3,
                const short* __restrict__ wt4, const float* __restrict__ fb1,
                const short* __restrict__ wt5, const float* __restrict__ fb2,
                float* __restrict__ ft)
{
    __shared__ __align__(16) float A_[16 * SA];
    __shared__ __align__(16) float Bb[16 * SA];
    const int tid  = threadIdx.x;
    const int row0 = blockIdx.x * 16;
    const int lane = tid & 63;
    const int wv_  = tid >> 6;
    const int quad = lane >> 4;
    const int ln15 = lane & 15;

    // stage g: A_[m][k], 14x16
    if (tid < 224) {
        const int k = tid / 16, m = tid % 16;
        A_[m * SA + k] = g[(size_t)(row0 + m) * 14 + k];
    }
    __syncthreads();

    {   // L1: 14 -> 64, relu. thread = col(64) x 4 rows.
        const int col = tid & 63;
        const int m0  = (tid >> 6) * 4;
        float acc[4];
        const float bv = b1[col];
#pragma unroll
        for (int r = 0; r < 4; ++r) acc[r] = bv;
#pragma unroll
        for (int k = 0; k < 14; ++k) {
            const float wv = w1[k * 64 + col];
#pragma unroll
            for (int r = 0; r < 4; ++r)
                acc[r] = fmaf(A_[(m0 + r) * SA + k], wv, acc[r]);
        }
#pragma unroll
        for (int r = 0; r < 4; ++r)
            Bb[(m0 + r) * SA + col] = fmaxf(acc[r], 0.f);
    }
    __syncthreads();

    {   // L2: 64 -> 128, relu. thread = col(128) x 8 rows.
        const int col = tid % 128;
        const int m0  = (tid / 128) * 8;
        float acc[8];
        const float bv = b2[col];
#pragma unroll
        for (int r = 0; r < 8; ++r) acc[r] = bv;
#pragma unroll 4
        for (int kq = 0; kq < 16; ++kq) {
            float wv[4];
#pragma unroll
            for (int jj = 0; jj < 4; ++jj) wv[jj] = w2[(4 * kq + jj) * 128 + col];
#pragma unroll
            for (int r = 0; r < 8; ++r) {
                const float4 a4 = *(const float4*)&Bb[(m0 + r) * SA + 4 * kq];
                acc[r] = fmaf(a4.x, wv[0], acc[r]);
                acc[r] = fmaf(a4.y, wv[1], acc[r]);
                acc[r] = fmaf(a4.z, wv[2], acc[r]);
                acc[r] = fmaf(a4.w, wv[3], acc[r]);
            }
        }
#pragma unroll
        for (int r = 0; r < 8; ++r)
            A_[(m0 + r) * SA + col] = fmaxf(acc[r], 0.f);
    }
    __syncthreads();

    {   // L3: 128 -> 256 MFMA, + b3, no relu. A_ -> Bb
        f32x4 acc[4] = {{0,0,0,0},{0,0,0,0},{0,0,0,0},{0,0,0,0}};
        mfma_acc<128>(wt3, A_, acc, wv_, quad, ln15);
        __syncthreads();
#pragma unroll
        for (int tt = 0; tt < 4; ++tt) {
            const int n = (wv_ * 4 + tt) * 16 + ln15;
            const float bv = b3[n];
#pragma unroll
            for (int r = 0; r < 4; ++r)
                Bb[(quad * 4 + r) * SA + n] = acc[tt][r] + bv;
        }
    }
    __syncthreads();

    {   // L4: 256 -> 256 MFMA, + fb1, relu. Bb -> A_
        f32x4 acc[4] = {{0,0,0,0},{0,0,0,0},{0,0,0,0},{0,0,0,0}};
        mfma_acc<256>(wt4, Bb, acc, wv_, quad, ln15);
        __syncthreads();
#pragma unroll
        for (int tt = 0; tt < 4; ++tt) {
            const int n = (wv_ * 4 + tt) * 16 + ln15;
            const float bv = fb1[n];
#pragma unroll
            for (int r = 0; r < 4; ++r)
                A_[(quad * 4 + r) * SA + n] = fmaxf(acc[tt][r] + bv, 0.f);
        }
    }
    __syncthreads();

    {   // L5: 256 -> 256 MFMA, + fb2 -> global ft
        f32x4 acc[4] = {{0,0,0,0},{0,0,0,0},{0,0,0,0},{0,0,0,0}};
        mfma_acc<256>(wt5, A_, acc, wv_, quad, ln15);
#pragma unroll
        for (int tt = 0; tt < 4; ++tt) {
            const int n = (wv_ * 4 + tt) * 16 + ln15;
            const float bv = fb2[n];
#pragma unroll
            for (int r = 0; r < 4; ++r)
                ft[(size_t)(row0 + quad * 4 + r) * 256 + n] = acc[tt][r] + bv;
        }
    }
}

// ---------------------------------------------------------------------------
// Splat (R6 verbatim): block = tile; 256 threads; 1-barrier chunk pipeline
// with global_load_lds double-buffered feats staging, 4ch x 4px phase-B tile.
// ---------------------------------------------------------------------------
__global__ __launch_bounds__(256)
void splat_kernel(const float* __restrict__ pp, const int* __restrict__ lists,
                  const int* __restrict__ counts, const float* __restrict__ feats,
                  float* __restrict__ out)
{
    __shared__ __align__(16) float feats_s[2][G_ * C_];   // 2 x 16 KB
    __shared__ __align__(16) float gws[2][G_ * 20];       // padded rows

    const int tid = threadIdx.x;
    const int bid = blockIdx.x;
    const int txi = bid % NTX;
    const int y   = (bid / NTX) % H_;
    const int b   = bid / (NTX * H_);
    const int x0  = txi * TW;
    const float fy = (float)y;
    const int cnt = min(counts[bid], CAP);
    const int* mylist = lists + (size_t)bid * CAP;
    const int gg  = tid >> 4;
    const int pxi = tid & 15;
    const int cg  = tid >> 2;
    const int pg  = tid & 3;
    const float fx = (float)(x0 + pxi);
    const int bN = b * N_;
    const int lane = tid & 63;
    const int wid  = tid >> 6;

    float acc[16];
#pragma unroll
    for (int t = 0; t < 16; ++t) acc[t] = 0.f;
    float densp = 0.f, uncp = 0.f;

    if (cnt > 0) {
#pragma unroll
        for (int rr = 0; rr < 4; ++rr) {
            const int r = 4 * wid + rr;
            const int n = mylist[min(r, cnt - 1)];
            gl_lds16(feats + (size_t)(bN + n) * C_ + lane * 4,
                     &feats_s[0][r * C_ + lane * 4]);
        }
        const int nchunks = (cnt + G_ - 1) / G_;
        for (int c = 0; c < nchunks; ++c) {
            const int buf = c & 1;
            const int m = min(G_, cnt - c * G_);
            if (gg < m) {
                const int n = mylist[c * G_ + gg];
                const float4 e0 = ((const float4*)pp)[(size_t)(bN + n) * 2 + 0];
                const float4 e1 = ((const float4*)pp)[(size_t)(bN + n) * 2 + 1];
                const float dyn = (fy - e0.y) * e0.w;
                const float dxn = (fx - e0.x) * e0.z;
                const float dist = dyn * dyn + dxn * dxn;
                float gv = 0.f;
                if (dist < 9.f) gv = __expf(-0.5f * dist) * e1.x;
                gws[buf][gg * 20 + pxi] = gv;
                densp += gv;
                uncp  += gv * e1.y;
            }
            __syncthreads();
            if (c + 1 < nchunks) {
#pragma unroll
                for (int rr = 0; rr < 4; ++rr) {
                    const int r = 4 * wid + rr;
                    const int n = mylist[min((c + 1) * G_ + r, cnt - 1)];
                    gl_lds16(feats + (size_t)(bN + n) * C_ + lane * 4,
                             &feats_s[buf ^ 1][r * C_ + lane * 4]);
                }
            }
            for (int q = 0; q < m; ++q) {
                const float4 fv  = *(const float4*)&feats_s[buf][q * C_ + 4 * cg];
                const float4 gw4 = *(const float4*)&gws[buf][q * 20 + 4 * pg];
                acc[0]  = fmaf(fv.x, gw4.x, acc[0]);
                acc[1]  = fmaf(fv.x, gw4.y, acc[1]);
                acc[2]  = fmaf(fv.x, gw4.z, acc[2]);
                acc[3]  = fmaf(fv.x, gw4.w, acc[3]);
                acc[4]  = fmaf(fv.y, gw4.x, acc[4]);
                acc[5]  = fmaf(fv.y, gw4.y, acc[5]);
                acc[6]  = fmaf(fv.y, gw4.z, acc[6]);
                acc[7]  = fmaf(fv.y, gw4.w, acc[7]);
                acc[8]  = fmaf(fv.z, gw4.x, acc[8]);
                acc[9]  = fmaf(fv.z, gw4.y, acc[9]);
                acc[10] = fmaf(fv.z, gw4.z, acc[10]);
                acc[11] = fmaf(fv.z, gw4.w, acc[11]);
                acc[12] = fmaf(fv.w, gw4.x, acc[12]);
                acc[13] = fmaf(fv.w, gw4.y, acc[13]);
                acc[14] = fmaf(fv.w, gw4.z, acc[14]);
                acc[15] = fmaf(fv.w, gw4.w, acc[15]);
            }
        }
    }

    __syncthreads();
    float* red_d = &feats_s[0][0];
    float* red_u = &feats_s[0][512];
    red_d[gg * 20 + pxi] = densp;
    red_u[gg * 20 + pxi] = uncp;
    __syncthreads();
    for (int s = 8; s > 0; s >>= 1) {
        if (gg < s) {
            red_d[gg * 20 + pxi] += red_d[(gg + s) * 20 + pxi];
            red_u[gg * 20 + pxi] += red_u[(gg + s) * 20 + pxi];
        }
        __syncthreads();
    }

    float dclip[4];
#pragma unroll
    for (int jj = 0; jj < 4; ++jj) dclip[jj] = fmaxf(red_d[4 * pg + jj], 1e-6f);

#pragma unroll
    for (int cc = 0; cc < 4; ++cc) {
        const int ch = 4 * cg + cc;
        float4 v;
        v.x = acc[cc * 4 + 0] / dclip[0];
        v.y = acc[cc * 4 + 1] / dclip[1];
        v.z = acc[cc * 4 + 2] / dclip[2];
        v.w = acc[cc * 4 + 3] / dclip[3];
        *(float4*)(out + (((size_t)b * C_ + ch) * H_ + y) * W_ + x0 + 4 * pg) = v;
    }
    if (tid < TW) {
        const size_t pix = ((size_t)b * H_ + y) * W_ + x0 + tid;
        float* unc_o = out + (size_t)B_ * C_ * H_ * W_;
        float* den_o = unc_o + (size_t)B_ * H_ * W_;
        const float d = fmaxf(red_d[tid], 1e-6f);
        unc_o[pix] = red_u[tid] / d;
        den_o[pix] = d;
    }
}

// ---------------------------------------------------------------------------
extern "C" void kernel_launch(void* const* d_in, const int* in_sizes, int n_in,
                              void* d_out, int out_size, void* d_ws, size_t ws_size,
                              hipStream_t stream)
{
    const float* g    = (const float*)d_in[0];
    const float* intr = (const float*)d_in[1];
    const float* w1   = (const float*)d_in[2];
    const float* b1   = (const float*)d_in[3];
    const float* w2   = (const float*)d_in[4];
    const float* b2   = (const float*)d_in[5];
    const float* w3   = (const float*)d_in[6];
    const float* b3   = (const float*)d_in[7];
    const float* fw1  = (const float*)d_in[8];
    const float* fb1  = (const float*)d_in[9];
    const float* fw2  = (const float*)d_in[10];
    const float* fb2  = (const float*)d_in[11];

    char* ws = (char*)d_ws;
    const int rows = B_ * N_;                              // 4096
    float* ft     = (float*)ws;                            // 4 MB
    float* pp     = ft + (size_t)rows * C_;                // 128 KB
    int*   counts = (int*)(pp + (size_t)8 * rows);         // 1408 ints
    int*   lists  = counts + NTILES;                       // 1408*1024 ints (5.8 MB)
    short* wt3    = (short*)(lists + (size_t)NTILES * CAP);// 128*256 bf16
    short* wt4    = wt3 + 128 * 256;                       // 256*256 bf16
    short* wt5    = wt4 + 256 * 256;                       // 256*256 bf16

    hipMemsetAsync(counts, 0, NTILES * sizeof(int), stream);
    parambin_kernel<<<dim3(rows / 8), dim3(256), 0, stream>>>(
        g, intr, w3, fw1, fw2, wt3, wt4, wt5, pp, counts, lists);
    mlp_kernel<<<dim3(rows / 16), dim3(256), 0, stream>>>(
        g, w1, b1, w2, b2, wt3, b3, wt4, fb1, wt5, fb2, ft);
    splat_kernel<<<dim3(NTILES), dim3(256), 0, stream>>>(pp, lists, counts, ft, (float*)d_out);
}